// Round 7
// baseline (224.798 us; speedup 1.0000x reference)
//
#include <hip/hip_runtime.h>
#include <cstdint>

#define NM   4096
#define NP   32768
#define NSEG 1024
#define GD   2304
#define HID  150
#define NPAD 160
#define KG32 72                      // GD/32
#define SEG_ELEMS (KG32 * 10 * 512)  // 368640 bf16 elems per packed W segment

typedef unsigned short u16;
typedef short s16x8 __attribute__((ext_vector_type(8)));   // 8 bf16 in 4 VGPRs
typedef float f32x4 __attribute__((ext_vector_type(4)));
typedef uint32_t u32x4 __attribute__((ext_vector_type(4)));

union Frag {
    uint32_t u[4];
    s16x8    v;
};

// one-instruction packed fp32->bf16 (RNE): D = {bf16(lo), bf16(hi)}
__device__ inline uint32_t cvtpk(float lo, float hi) {
    uint32_t r;
    asm("v_cvt_pk_bf16_f32 %0, %1, %2" : "=v"(r) : "v"(lo), "v"(hi));
    return r;
}

__device__ inline f32x4 mfma16(s16x8 a, s16x8 b, f32x4 c) {
    return __builtin_amdgcn_mfma_f32_16x16x32_bf16(a, b, c, 0, 0, 0);
}

// elementwise bf16 product of two 8-elem chunks -> bf16 A-fragment
__device__ inline s16x8 prodpack(u32x4 iu, u32x4 ju) {
    Frag f;
#pragma unroll
    for (int m = 0; m < 4; ++m) {
        uint32_t x = iu[m], y = ju[m];
        float lo = __builtin_bit_cast(float, x << 16) *
                   __builtin_bit_cast(float, y << 16);
        float hi = __builtin_bit_cast(float, x & 0xffff0000u) *
                   __builtin_bit_cast(float, y & 0xffff0000u);
        f.u[m] = cvtpk(lo, hi);
    }
    return f.v;
}

// ---------------------------------------------------------------------------
// Pack W1 blocks into MFMA B-fragment order (coalesced: n lane-fastest).
// Segment 0: W1_prod (rows 4608..6911), 1: W1_i (0..2303), 2: W1_j (2304..4607)
// Layout per segment: [kg32][nf(10)][lane(64)][j(8)] bf16, zero-pad cols>=150.
// B-frag mapping (16x16x32): n = lane&15, k = (lane>>4)*8 + j.
// ---------------------------------------------------------------------------
__global__ void prep_pack_kernel(const float* __restrict__ W1,
                                 u16* __restrict__ wpack) {
    int idx = blockIdx.x * 256 + threadIdx.x;   // ((seg*72+kg)*10+nf)*64+lane
    if (idx >= 3 * KG32 * 10 * 64) return;
    int lane = idx & 63;
    int t    = idx >> 6;
    int nf   = t % 10;
    int sk   = t / 10;
    int seg  = sk / KG32, kg = sk % KG32;
    int kbase = (seg == 0) ? 2 * GD : ((seg == 1) ? 0 : GD);
    int n    = nf * 16 + (lane & 15);
    int krow = kbase + kg * 32 + ((lane >> 4) << 3);
    u32x4 d = (u32x4){0u, 0u, 0u, 0u};
    if (n < HID) {
#pragma unroll
        for (int jj = 0; jj < 4; ++jj) {
            float v0 = W1[(size_t)(krow + 2 * jj) * HID + n];
            float v1 = W1[(size_t)(krow + 2 * jj + 1) * HID + n];
            d[jj] = cvtpk(v0, v1);
        }
    }
    *(u32x4*)(wpack + (size_t)idx * 8) = d;
}

// ---------------------------------------------------------------------------
// Fused: speaker/bias tables + counting-sort of pairs by mention_id.
// ONE block, 1024 threads. LDS hist (4096 bins) -> LDS scan -> scatter with
// LDS cursors (no global atomics, no extra launches).
// ---------------------------------------------------------------------------
__global__ __launch_bounds__(1024)
void prep_sort_kernel(const float* __restrict__ spk,
                      const float* __restrict__ W1,
                      const float* __restrict__ b1,
                      const float* __restrict__ W2,
                      const int* __restrict__ mids,
                      float* __restrict__ phib,
                      float* __restrict__ w2pad,
                      int* __restrict__ perm) {
    __shared__ int cnt[NM];    // 16 KB: hist, then scatter cursor
    __shared__ int bas[NM];    // 16 KB: exclusive prefix
    __shared__ int lsum[1024]; //  4 KB

    const int t = threadIdx.x;

    // --- tables (independent, tiny) ---
    if (t < 3 * NPAD) {
        int s = t / NPAD, n = t - s * NPAD;
        float a = 0.f;
        if (n < HID) {
            for (int d = 0; d < 20; ++d)
                a = fmaf(spk[s * 20 + d], W1[(size_t)(3 * GD + d) * HID + n], a);
            a += b1[n];
        }
        phib[t] = a;
    } else if (t < 4 * NPAD) {
        int n = t - 3 * NPAD;
        w2pad[n] = (n < HID) ? W2[n] : 0.f;
    }

    // --- zero hist ---
#pragma unroll
    for (int j = 0; j < 4; ++j) cnt[t + j * 1024] = 0;
    __syncthreads();

    // --- hist (LDS atomics) ---
    for (int p = t; p < NP; p += 1024) atomicAdd(&cnt[mids[p]], 1);
    __syncthreads();

    // --- scan: thread t owns bins [4t,4t+4) ---
    int v[4];
    int s = 0;
#pragma unroll
    for (int j = 0; j < 4; ++j) { v[j] = cnt[4 * t + j]; s += v[j]; }
    int val = s;
    lsum[t] = val;
    __syncthreads();
    for (int off = 1; off < 1024; off <<= 1) {
        int x = (t >= off) ? lsum[t - off] : 0;
        __syncthreads();
        val += x;
        lsum[t] = val;
        __syncthreads();
    }
    int run = val - s;  // exclusive prefix of this thread's chunk
#pragma unroll
    for (int j = 0; j < 4; ++j) {
        bas[4 * t + j] = run;
        run += v[j];
        cnt[4 * t + j] = 0;  // scatter cursor
    }
    __syncthreads();

    // --- scatter ---
    for (int p = t; p < NP; p += 1024) {
        int m = mids[p];
        int pos = bas[m] + atomicAdd(&cnt[m], 1);
        perm[pos] = p;
    }
}

// ---------------------------------------------------------------------------
// APre[m, 0:160)   = g_i[m] @ W1_i   (bf16 MFMA)
// APre[m, 160:320) = g_i[m] @ W1_j
// Block = 256 thr = 4 waves = 4-way K-split of ONE 16-row group; partials
// merged through LDS by wave 0 (one barrier at the end).
// Grid (256 row-tiles, 2 ng) x 256 thr = 2048 waves, 18 phases each.
// Pipeline: A depth-3 (a0..a2), B depth-2 (b0,b1); LDB issued before LDA.
// ng==0 waves also emit the bf16 copy of g_i (gbf) for their K-quarter.
// ---------------------------------------------------------------------------
struct A2 { f32x4 x0, x1; };

__launch_bounds__(256)
__global__ void gemm_pre_kernel(const float* __restrict__ gi,
                                const u16* __restrict__ wpackIJ,
                                u16* __restrict__ gbf,
                                float* __restrict__ APre) {
    const int tid = threadIdx.x;
    const int kh = tid >> 6, lane = tid & 63;
    const int quad = lane >> 4, l15 = lane & 15;
    const int mt = blockIdx.x, ng = blockIdx.y;
    const u16* wp = wpackIJ + (size_t)ng * SEG_ELEMS + lane * 8;
    const int row = mt * 16 + l15;

    __shared__ float xch[3][64][44];  // 33,792 B partial-merge buffer (padded)

    f32x4 acc[10];
#pragma unroll
    for (int b = 0; b < 10; ++b) acc[b] = (f32x4){0.f, 0.f, 0.f, 0.f};

    const float* ap = gi + (size_t)row * GD + quad * 8;
    u16* gb = gbf + (size_t)row * GD + quad * 8;
    const bool emit = (ng == 0);
    const int u0 = kh * 18;  // 18 kg32 steps per K-quarter

    A2 a0, a1, a2;
    Frag b0[10], b1[10];

#define LDA(ax, k) { ax.x0 = *(const f32x4*)(ap + (u0 + (k)) * 32); \
                     ax.x1 = *(const f32x4*)(ap + (u0 + (k)) * 32 + 4); }
#define LDBP(bb, k) { const u16* wn = wp + (size_t)(u0 + (k)) * 5120; \
        _Pragma("unroll") for (int nf = 0; nf < 10; ++nf) \
            bb[nf].v = *(const s16x8*)(const void*)(wn + nf * 512); }
#define PHP(k, ax, bb) { \
        Frag a; \
        a.u[0] = cvtpk(ax.x0[0], ax.x0[1]); a.u[1] = cvtpk(ax.x0[2], ax.x0[3]); \
        a.u[2] = cvtpk(ax.x1[0], ax.x1[1]); a.u[3] = cvtpk(ax.x1[2], ax.x1[3]); \
        if (emit) *(u32x4*)(gb + (u0 + (k)) * 32) = *(const u32x4*)a.u; \
        _Pragma("unroll") for (int nf = 0; nf < 10; ++nf) \
            acc[nf] = mfma16(a.v, bb[nf].v, acc[nf]); }

    // prologue
    LDBP(b0, 0); LDBP(b1, 1);
    LDA(a0, 0); LDA(a1, 1); LDA(a2, 2);

    // phases 0..11 (2 x unroll-6; LDB before LDA each phase)
#pragma unroll 1
    for (int t = 0; t < 2; ++t) {
        const int kb = t * 6;
        PHP(kb + 0, a0, b0); LDBP(b0, kb + 2); LDA(a0, kb + 3);
        PHP(kb + 1, a1, b1); LDBP(b1, kb + 3); LDA(a1, kb + 4);
        PHP(kb + 2, a2, b0); LDBP(b0, kb + 4); LDA(a2, kb + 5);
        PHP(kb + 3, a0, b1); LDBP(b1, kb + 5); LDA(a0, kb + 6);
        PHP(kb + 4, a1, b0); LDBP(b0, kb + 6); LDA(a1, kb + 7);
        PHP(kb + 5, a2, b1); LDBP(b1, kb + 7); LDA(a2, kb + 8);
    }
    // tail: phases 12..17
    PHP(12, a0, b0); LDBP(b0, 14); LDA(a0, 15);
    PHP(13, a1, b1); LDBP(b1, 15); LDA(a1, 16);
    PHP(14, a2, b0); LDBP(b0, 16); LDA(a2, 17);
    PHP(15, a0, b1); LDBP(b1, 17);
    PHP(16, a1, b0);
    PHP(17, a2, b1);

#undef LDA
#undef LDBP
#undef PHP

    // K-split merge: waves 1..3 deposit, wave 0 sums + stores.
    if (kh != 0) {
        float* dst = &xch[kh - 1][lane][0];
#pragma unroll
        for (int nf = 0; nf < 10; ++nf)
            *(f32x4*)(dst + nf * 4) = acc[nf];
    }
    __syncthreads();
    if (kh == 0) {
#pragma unroll
        for (int k = 0; k < 3; ++k) {
            const float* src = &xch[k][lane][0];
#pragma unroll
            for (int nf = 0; nf < 10; ++nf)
                acc[nf] += *(const f32x4*)(src + nf * 4);
        }
        // C/D layout: col = lane&15, row = (lane>>4)*4 + reg
        const int colbase = ng * NPAD + l15;
        float* Ap = APre + (size_t)(mt * 16 + quad * 4) * 320 + colbase;
#pragma unroll
        for (int nf = 0; nf < 10; ++nf)
#pragma unroll
            for (int r = 0; r < 4; ++r)
                Ap[(size_t)r * 320 + nf * 16] = acc[nf][r];
    }
}

// ---------------------------------------------------------------------------
// Main pair kernel over mid-sorted pair order (perm). Sorting makes each
// wave's 32 i-rows collapse to ~4 distinct rows -> i-side gathers become
// same-line broadcasts (L1/L2 hits); j stays random. Structure = r2's
// proven pipeline: gathers depth-3, B depth-2, no LDS/barriers/setprio.
// Grid 512 x 128 thr; perm is an exact permutation of NP (no guards).
// ---------------------------------------------------------------------------
struct G4 { u32x4 i0, j0, i1, j1; };

__launch_bounds__(128)
__global__ void gemm_pairs_kernel(const u16* __restrict__ gbf,
                                  const u16* __restrict__ wpackP,
                                  const float* __restrict__ APre,
                                  const float* __restrict__ phib,
                                  const float* __restrict__ w2pad,
                                  const float* __restrict__ mscore,
                                  const float* __restrict__ b2,
                                  const int* __restrict__ mids,
                                  const int* __restrict__ aids,
                                  const int* __restrict__ slab,
                                  const int* __restrict__ perm,
                                  float* __restrict__ scores) {
    const int tid = threadIdx.x;
    const int wave = tid >> 6, lane = tid & 63;
    const int quad = lane >> 4, l15 = lane & 15;
    const int base = blockIdx.x * 64 + wave * 32;

    f32x4 acc[2][10];
#pragma unroll
    for (int a = 0; a < 2; ++a)
#pragma unroll
        for (int b = 0; b < 10; ++b) acc[a][b] = (f32x4){0.f, 0.f, 0.f, 0.f};

    const int p0 = perm[base + l15], p1 = perm[base + 16 + l15];
    const u16* ip0 = gbf + (size_t)mids[p0] * GD + quad * 8;
    const u16* jp0 = gbf + (size_t)aids[p0] * GD + quad * 8;
    const u16* ip1 = gbf + (size_t)mids[p1] * GD + quad * 8;
    const u16* jp1 = gbf + (size_t)aids[p1] * GD + quad * 8;
    const u16* wl = wpackP + lane * 8;

    G4 g0, g1, g2;
    Frag b0[10], b1[10];

#define LDG(g, k) { const int off = (k) * 32; \
        g.i0 = *(const u32x4*)(ip0 + off); g.j0 = *(const u32x4*)(jp0 + off); \
        g.i1 = *(const u32x4*)(ip1 + off); g.j1 = *(const u32x4*)(jp1 + off); }
#define LDB(bb, k) { const u16* wn = wl + (size_t)(k) * 5120; \
        _Pragma("unroll") for (int nf = 0; nf < 10; ++nf) \
            bb[nf].v = *(const s16x8*)(const void*)(wn + nf * 512); }
#define PH(g, bb) { \
        s16x8 a0 = prodpack(g.i0, g.j0); \
        s16x8 a1 = prodpack(g.i1, g.j1); \
        _Pragma("unroll") for (int nf = 0; nf < 10; ++nf) { \
            acc[0][nf] = mfma16(a0, bb[nf].v, acc[0][nf]); \
            acc[1][nf] = mfma16(a1, bb[nf].v, acc[1][nf]); } }

    // prologue: gathers depth-3 (miss latency), B depth-2 (L2 latency)
    LDG(g0, 0); LDG(g1, 1); LDG(g2, 2);
    LDB(b0, 0); LDB(b1, 1);

    // phases 0..65 (11 x unroll-6: buffer parity/rotation compile-time)
#pragma unroll 1
    for (int t = 0; t < 11; ++t) {
        const int kb = t * 6;
        PH(g0, b0); LDG(g0, kb + 3); LDB(b0, kb + 2);
        PH(g1, b1); LDG(g1, kb + 4); LDB(b1, kb + 3);
        PH(g2, b0); LDG(g2, kb + 5); LDB(b0, kb + 4);
        PH(g0, b1); LDG(g0, kb + 6); LDB(b1, kb + 5);
        PH(g1, b0); LDG(g1, kb + 7); LDB(b0, kb + 6);
        PH(g2, b1); LDG(g2, kb + 8); LDB(b1, kb + 7);
    }
    // tail: phases 66..71
    PH(g0, b0); LDG(g0, 69); LDB(b0, 68);
    PH(g1, b1); LDG(g1, 70); LDB(b1, 69);
    PH(g2, b0); LDG(g2, 71); LDB(b0, 70);
    PH(g0, b1); LDB(b1, 71);
    PH(g1, b0);
    PH(g2, b1);

#undef LDG
#undef LDB
#undef PH

    // Epilogue: bias + relu + W2-dot + cross-lane reduce, write scores
    float w2v[10];
#pragma unroll
    for (int nf = 0; nf < 10; ++nf) w2v[nf] = w2pad[nf * 16 + l15];
    const float b2v = b2[0];

#pragma unroll
    for (int mf = 0; mf < 2; ++mf)
#pragma unroll
        for (int r = 0; r < 4; ++r) {
            const int p  = perm[base + mf * 16 + quad * 4 + r];
            const int mi = mids[p], ai = aids[p], sp = slab[p];
            const float* Ai = APre + (size_t)mi * 320;
            const float* Bj = APre + (size_t)ai * 320 + NPAD;
            const float* Ph = phib + sp * NPAD;
            float partial = 0.f;
#pragma unroll
            for (int nf = 0; nf < 10; ++nf) {
                const int c = nf * 16 + l15;
                float h = acc[mf][nf][r] + Ai[c] + Bj[c] + Ph[c];
                h = fmaxf(h, 0.f);
                partial = fmaf(h, w2v[nf], partial);
            }
            partial += __shfl_xor(partial, 1);
            partial += __shfl_xor(partial, 2);
            partial += __shfl_xor(partial, 4);
            partial += __shfl_xor(partial, 8);
            if (l15 == 0)
                scores[p] = partial + b2v + mscore[mi] + mscore[ai];
        }
}

// ---------------------------------------------------------------------------
// Ragged per-span softmax with epsilon logit 0. One wave per segment;
// segment_ids is sorted -> binary search the range.
// ---------------------------------------------------------------------------
__global__ void seg_softmax_kernel(const float* __restrict__ scores,
                                   const int* __restrict__ seg,
                                   float* __restrict__ out) {
    const int s = blockIdx.x;
    const int lane = threadIdx.x;
    int lo = 0, hi = NP;
    while (lo < hi) { int mid = (lo + hi) >> 1; if (seg[mid] < s) lo = mid + 1; else hi = mid; }
    const int start = lo;
    int lo2 = start, hi2 = NP;
    while (lo2 < hi2) { int mid = (lo2 + hi2) >> 1; if (seg[mid] <= s) lo2 = mid + 1; else hi2 = mid; }
    const int end = lo2;

    float m = 0.f;  // epsilon logit 0 participates in the max
    for (int i = start + lane; i < end; i += 64) m = fmaxf(m, scores[i]);
#pragma unroll
    for (int msk = 1; msk < 64; msk <<= 1) m = fmaxf(m, __shfl_xor(m, msk));

    float sum = 0.f;
    for (int i = start + lane; i < end; i += 64) sum += __expf(scores[i] - m);
#pragma unroll
    for (int msk = 1; msk < 64; msk <<= 1) sum += __shfl_xor(sum, msk);

    const float epse = __expf(-m);
    const float inv  = 1.f / (sum + epse);
    for (int i = start + lane; i < end; i += 64) out[i] = __expf(scores[i] - m) * inv;
    if (lane == 0) out[NP + s] = epse * inv;
}

// ---------------------------------------------------------------------------
extern "C" void kernel_launch(void* const* d_in, const int* in_sizes, int n_in,
                              void* d_out, int out_size, void* d_ws, size_t ws_size,
                              hipStream_t stream) {
    const float* gi     = (const float*)d_in[0];
    const float* mscore = (const float*)d_in[1];
    const float* spk    = (const float*)d_in[2];
    const float* W1     = (const float*)d_in[3];
    const float* b1     = (const float*)d_in[4];
    const float* W2     = (const float*)d_in[5];
    const float* b2     = (const float*)d_in[6];
    const int*   mids   = (const int*)d_in[7];
    const int*   aids   = (const int*)d_in[8];
    const int*   slab   = (const int*)d_in[9];
    const int*   segs   = (const int*)d_in[10];
    float* out = (float*)d_out;

    char* w = (char*)d_ws;
    u16*   gbf    = (u16*)w;                               // 18,874,368 B
    u16*   wpack  = (u16*)(w + 18874368);                  //  2,211,840 B (3 segs)
    float* APre   = (float*)(w + 21086208);                //  5,242,880 B
    float* scores = (float*)(w + 26329088);                //    131,072 B
    float* phib   = (float*)(w + 26460160);                //      1,920 B
    float* w2pad  = (float*)(w + 26462080);                //        640 B
    int*   perm   = (int*)(w + 26462720);                  //    131,072 B

    prep_pack_kernel<<<dim3((3 * KG32 * 10 * 64 + 255) / 256), dim3(256), 0, stream>>>(W1, wpack);
    prep_sort_kernel<<<dim3(1), dim3(1024), 0, stream>>>(spk, W1, b1, W2, mids,
                                                         phib, w2pad, perm);
    gemm_pre_kernel<<<dim3(256, 2), dim3(256), 0, stream>>>(gi, wpack + SEG_ELEMS, gbf, APre);
    gemm_pairs_kernel<<<dim3(512), dim3(128), 0, stream>>>(gbf, wpack, APre, phib, w2pad,
                                                           mscore, b2, mids, aids, slab,
                                                           perm, scores);
    seg_softmax_kernel<<<dim3(NSEG), dim3(64), 0, stream>>>(scores, segs, out);
}

// Round 8
// 192.362 us; speedup vs baseline: 1.1686x; 1.1686x over previous
//
#include <hip/hip_runtime.h>
#include <cstdint>

#define NM   4096
#define NP   32768
#define NSEG 1024
#define GD   2304
#define HID  150
#define NPAD 160
#define KG32 72                      // GD/32
#define SEG_ELEMS (KG32 * 10 * 512)  // 368640 bf16 elems per packed W segment

typedef unsigned short u16;
typedef short s16x8 __attribute__((ext_vector_type(8)));   // 8 bf16 in 4 VGPRs
typedef float f32x4 __attribute__((ext_vector_type(4)));
typedef uint32_t u32x4 __attribute__((ext_vector_type(4)));

union Frag {
    uint32_t u[4];
    s16x8    v;
};

// one-instruction packed fp32->bf16 (RNE): D = {bf16(lo), bf16(hi)}
__device__ inline uint32_t cvtpk(float lo, float hi) {
    uint32_t r;
    asm("v_cvt_pk_bf16_f32 %0, %1, %2" : "=v"(r) : "v"(lo), "v"(hi));
    return r;
}

__device__ inline f32x4 mfma16(s16x8 a, s16x8 b, f32x4 c) {
    return __builtin_amdgcn_mfma_f32_16x16x32_bf16(a, b, c, 0, 0, 0);
}

// elementwise bf16 product of two 8-elem chunks -> bf16 A-fragment
__device__ inline s16x8 prodpack(u32x4 iu, u32x4 ju) {
    Frag f;
#pragma unroll
    for (int m = 0; m < 4; ++m) {
        uint32_t x = iu[m], y = ju[m];
        float lo = __builtin_bit_cast(float, x << 16) *
                   __builtin_bit_cast(float, y << 16);
        float hi = __builtin_bit_cast(float, x & 0xffff0000u) *
                   __builtin_bit_cast(float, y & 0xffff0000u);
        f.u[m] = cvtpk(lo, hi);
    }
    return f.v;
}

// ---------------------------------------------------------------------------
// Fused prep: blocks 0..539 pack W1 into MFMA B-fragment order (coalesced,
// n lane-fastest); blocks 540..542 build phib/w2pad tables.
// Segment 0: W1_prod (rows 4608..6911), 1: W1_i (0..2303), 2: W1_j (2304..4607)
// Layout per segment: [kg32][nf(10)][lane(64)][j(8)] bf16, zero-pad cols>=150.
// B-frag mapping (16x16x32): n = lane&15, k = (lane>>4)*8 + j.
// ---------------------------------------------------------------------------
__launch_bounds__(256)
__global__ void prep_kernel(const float* __restrict__ W1,
                            const float* __restrict__ spk,
                            const float* __restrict__ b1,
                            const float* __restrict__ W2,
                            u16* __restrict__ wpack,
                            float* __restrict__ phib,
                            float* __restrict__ w2pad) {
    const int b = blockIdx.x;
    if (b < 540) {
        int idx = b * 256 + threadIdx.x;   // ((seg*72+kg)*10+nf)*64+lane
        int lane = idx & 63;
        int t    = idx >> 6;
        int nf   = t % 10;
        int sk   = t / 10;
        int seg  = sk / KG32, kg = sk % KG32;
        int kbase = (seg == 0) ? 2 * GD : ((seg == 1) ? 0 : GD);
        int n    = nf * 16 + (lane & 15);
        int krow = kbase + kg * 32 + ((lane >> 4) << 3);
        u32x4 d = (u32x4){0u, 0u, 0u, 0u};
        if (n < HID) {
#pragma unroll
            for (int jj = 0; jj < 4; ++jj) {
                float v0 = W1[(size_t)(krow + 2 * jj) * HID + n];
                float v1 = W1[(size_t)(krow + 2 * jj + 1) * HID + n];
                d[jj] = cvtpk(v0, v1);
            }
        }
        *(u32x4*)(wpack + (size_t)idx * 8) = d;
    } else {
        int t = (b - 540) * 256 + threadIdx.x;
        if (t < 3 * NPAD) {
            int s = t / NPAD, n = t - s * NPAD;
            float a = 0.f;
            if (n < HID) {
                for (int d = 0; d < 20; ++d)
                    a = fmaf(spk[s * 20 + d], W1[(size_t)(3 * GD + d) * HID + n], a);
                a += b1[n];
            }
            phib[t] = a;
        } else if (t < 4 * NPAD) {
            int n = t - 3 * NPAD;
            w2pad[n] = (n < HID) ? W2[n] : 0.f;
        }
    }
}

// ---------------------------------------------------------------------------
// APre[m, 0:160)   = g_i[m] @ W1_i   (bf16 MFMA)
// APre[m, 160:320) = g_i[m] @ W1_j
// Block = 256 thr = 4 waves = 4-way K-split of ONE 16-row group; partials
// merged through LDS by wave 0 (one barrier at the end).
// Grid (256 row-tiles, 2 ng) x 256 thr = 2048 waves, 18 phases each.
// Pipeline: A depth-3 (a0..a2), B depth-2 (b0,b1); LDB issued before LDA.
// ng==0 waves also emit the bf16 copy of g_i (gbf) for their K-quarter.
// ---------------------------------------------------------------------------
struct A2 { f32x4 x0, x1; };

__launch_bounds__(256)
__global__ void gemm_pre_kernel(const float* __restrict__ gi,
                                const u16* __restrict__ wpackIJ,
                                u16* __restrict__ gbf,
                                float* __restrict__ APre) {
    const int tid = threadIdx.x;
    const int kh = tid >> 6, lane = tid & 63;
    const int quad = lane >> 4, l15 = lane & 15;
    const int mt = blockIdx.x, ng = blockIdx.y;
    const u16* wp = wpackIJ + (size_t)ng * SEG_ELEMS + lane * 8;
    const int row = mt * 16 + l15;

    __shared__ float xch[3][64][44];  // 33,792 B partial-merge buffer (padded)

    f32x4 acc[10];
#pragma unroll
    for (int b = 0; b < 10; ++b) acc[b] = (f32x4){0.f, 0.f, 0.f, 0.f};

    const float* ap = gi + (size_t)row * GD + quad * 8;
    u16* gb = gbf + (size_t)row * GD + quad * 8;
    const bool emit = (ng == 0);
    const int u0 = kh * 18;  // 18 kg32 steps per K-quarter

    A2 a0, a1, a2;
    Frag b0[10], b1[10];

#define LDA(ax, k) { ax.x0 = *(const f32x4*)(ap + (u0 + (k)) * 32); \
                     ax.x1 = *(const f32x4*)(ap + (u0 + (k)) * 32 + 4); }
#define LDBP(bb, k) { const u16* wn = wp + (size_t)(u0 + (k)) * 5120; \
        _Pragma("unroll") for (int nf = 0; nf < 10; ++nf) \
            bb[nf].v = *(const s16x8*)(const void*)(wn + nf * 512); }
#define PHP(k, ax, bb) { \
        Frag a; \
        a.u[0] = cvtpk(ax.x0[0], ax.x0[1]); a.u[1] = cvtpk(ax.x0[2], ax.x0[3]); \
        a.u[2] = cvtpk(ax.x1[0], ax.x1[1]); a.u[3] = cvtpk(ax.x1[2], ax.x1[3]); \
        if (emit) *(u32x4*)(gb + (u0 + (k)) * 32) = *(const u32x4*)a.u; \
        _Pragma("unroll") for (int nf = 0; nf < 10; ++nf) \
            acc[nf] = mfma16(a.v, bb[nf].v, acc[nf]); }

    // prologue
    LDBP(b0, 0); LDBP(b1, 1);
    LDA(a0, 0); LDA(a1, 1); LDA(a2, 2);

    // phases 0..11 (2 x unroll-6; LDB before LDA each phase)
#pragma unroll 1
    for (int t = 0; t < 2; ++t) {
        const int kb = t * 6;
        PHP(kb + 0, a0, b0); LDBP(b0, kb + 2); LDA(a0, kb + 3);
        PHP(kb + 1, a1, b1); LDBP(b1, kb + 3); LDA(a1, kb + 4);
        PHP(kb + 2, a2, b0); LDBP(b0, kb + 4); LDA(a2, kb + 5);
        PHP(kb + 3, a0, b1); LDBP(b1, kb + 5); LDA(a0, kb + 6);
        PHP(kb + 4, a1, b0); LDBP(b0, kb + 6); LDA(a1, kb + 7);
        PHP(kb + 5, a2, b1); LDBP(b1, kb + 7); LDA(a2, kb + 8);
    }
    // tail: phases 12..17
    PHP(12, a0, b0); LDBP(b0, 14); LDA(a0, 15);
    PHP(13, a1, b1); LDBP(b1, 15); LDA(a1, 16);
    PHP(14, a2, b0); LDBP(b0, 16); LDA(a2, 17);
    PHP(15, a0, b1); LDBP(b1, 17);
    PHP(16, a1, b0);
    PHP(17, a2, b1);

#undef LDA
#undef LDBP
#undef PHP

    // K-split merge: waves 1..3 deposit, wave 0 sums + stores.
    if (kh != 0) {
        float* dst = &xch[kh - 1][lane][0];
#pragma unroll
        for (int nf = 0; nf < 10; ++nf)
            *(f32x4*)(dst + nf * 4) = acc[nf];
    }
    __syncthreads();
    if (kh == 0) {
#pragma unroll
        for (int k = 0; k < 3; ++k) {
            const float* src = &xch[k][lane][0];
#pragma unroll
            for (int nf = 0; nf < 10; ++nf)
                acc[nf] += *(const f32x4*)(src + nf * 4);
        }
        // C/D layout: col = lane&15, row = (lane>>4)*4 + reg
        const int colbase = ng * NPAD + l15;
        float* Ap = APre + (size_t)(mt * 16 + quad * 4) * 320 + colbase;
#pragma unroll
        for (int nf = 0; nf < 10; ++nf)
#pragma unroll
            for (int r = 0; r < 4; ++r)
                Ap[(size_t)r * 320 + nf * 16] = acc[nf][r];
    }
}

// ---------------------------------------------------------------------------
// Main pair kernel: scores[p] = s_i + s_j + b2 + W2 . relu( (i*j)@W1_prod
//                                + APre_i + APre_j + phib[spk] )
// Grid 512 x 128 thr (1024 waves, 32 pairs/wave, full K per wave).
// r2's proven pipeline: gathers depth-3 (g0..g2), B depth-2 (b0,b1),
// no LDS, no barriers, no setprio, direct pair indexing (no sort).
// ---------------------------------------------------------------------------
struct G4 { u32x4 i0, j0, i1, j1; };

__launch_bounds__(128)
__global__ void gemm_pairs_kernel(const u16* __restrict__ gbf,
                                  const u16* __restrict__ wpackP,
                                  const float* __restrict__ APre,
                                  const float* __restrict__ phib,
                                  const float* __restrict__ w2pad,
                                  const float* __restrict__ mscore,
                                  const float* __restrict__ b2,
                                  const int* __restrict__ mids,
                                  const int* __restrict__ aids,
                                  const int* __restrict__ slab,
                                  float* __restrict__ scores) {
    const int tid = threadIdx.x;
    const int wave = tid >> 6, lane = tid & 63;
    const int quad = lane >> 4, l15 = lane & 15;
    const int base = blockIdx.x * 64 + wave * 32;

    f32x4 acc[2][10];
#pragma unroll
    for (int a = 0; a < 2; ++a)
#pragma unroll
        for (int b = 0; b < 10; ++b) acc[a][b] = (f32x4){0.f, 0.f, 0.f, 0.f};

    const int p0 = base + l15, p1 = base + 16 + l15;
    const u16* ip0 = gbf + (size_t)mids[p0] * GD + quad * 8;
    const u16* jp0 = gbf + (size_t)aids[p0] * GD + quad * 8;
    const u16* ip1 = gbf + (size_t)mids[p1] * GD + quad * 8;
    const u16* jp1 = gbf + (size_t)aids[p1] * GD + quad * 8;
    const u16* wl = wpackP + lane * 8;

    G4 g0, g1, g2;
    Frag b0[10], b1[10];

#define LDG(g, k) { const int off = (k) * 32; \
        g.i0 = *(const u32x4*)(ip0 + off); g.j0 = *(const u32x4*)(jp0 + off); \
        g.i1 = *(const u32x4*)(ip1 + off); g.j1 = *(const u32x4*)(jp1 + off); }
#define LDB(bb, k) { const u16* wn = wl + (size_t)(k) * 5120; \
        _Pragma("unroll") for (int nf = 0; nf < 10; ++nf) \
            bb[nf].v = *(const s16x8*)(const void*)(wn + nf * 512); }
#define PH(g, bb) { \
        s16x8 a0 = prodpack(g.i0, g.j0); \
        s16x8 a1 = prodpack(g.i1, g.j1); \
        _Pragma("unroll") for (int nf = 0; nf < 10; ++nf) { \
            acc[0][nf] = mfma16(a0, bb[nf].v, acc[0][nf]); \
            acc[1][nf] = mfma16(a1, bb[nf].v, acc[1][nf]); } }

    // prologue: gathers depth-3 (miss latency), B depth-2 (L2 latency)
    LDG(g0, 0); LDG(g1, 1); LDG(g2, 2);
    LDB(b0, 0); LDB(b1, 1);

    // phases 0..65 (11 x unroll-6: buffer parity/rotation compile-time)
#pragma unroll 1
    for (int t = 0; t < 11; ++t) {
        const int kb = t * 6;
        PH(g0, b0); LDG(g0, kb + 3); LDB(b0, kb + 2);
        PH(g1, b1); LDG(g1, kb + 4); LDB(b1, kb + 3);
        PH(g2, b0); LDG(g2, kb + 5); LDB(b0, kb + 4);
        PH(g0, b1); LDG(g0, kb + 6); LDB(b1, kb + 5);
        PH(g1, b0); LDG(g1, kb + 7); LDB(b0, kb + 6);
        PH(g2, b1); LDG(g2, kb + 8); LDB(b1, kb + 7);
    }
    // tail: phases 66..71
    PH(g0, b0); LDG(g0, 69); LDB(b0, 68);
    PH(g1, b1); LDG(g1, 70); LDB(b1, 69);
    PH(g2, b0); LDG(g2, 71); LDB(b0, 70);
    PH(g0, b1); LDB(b1, 71);
    PH(g1, b0);
    PH(g2, b1);

#undef LDG
#undef LDB
#undef PH

    // Epilogue: bias + relu + W2-dot + cross-lane reduce, write scores
    float w2v[10];
#pragma unroll
    for (int nf = 0; nf < 10; ++nf) w2v[nf] = w2pad[nf * 16 + l15];
    const float b2v = b2[0];

#pragma unroll
    for (int mf = 0; mf < 2; ++mf)
#pragma unroll
        for (int r = 0; r < 4; ++r) {
            const int p  = base + mf * 16 + quad * 4 + r;
            const int mi = mids[p], ai = aids[p], sp = slab[p];
            const float* Ai = APre + (size_t)mi * 320;
            const float* Bj = APre + (size_t)ai * 320 + NPAD;
            const float* Ph = phib + sp * NPAD;
            float partial = 0.f;
#pragma unroll
            for (int nf = 0; nf < 10; ++nf) {
                const int c = nf * 16 + l15;
                float h = acc[mf][nf][r] + Ai[c] + Bj[c] + Ph[c];
                h = fmaxf(h, 0.f);
                partial = fmaf(h, w2v[nf], partial);
            }
            partial += __shfl_xor(partial, 1);
            partial += __shfl_xor(partial, 2);
            partial += __shfl_xor(partial, 4);
            partial += __shfl_xor(partial, 8);
            if (l15 == 0)
                scores[p] = partial + b2v + mscore[mi] + mscore[ai];
        }
}

// ---------------------------------------------------------------------------
// Ragged per-span softmax with epsilon logit 0. One wave per segment;
// segment_ids is sorted -> binary search the range.
// ---------------------------------------------------------------------------
__global__ void seg_softmax_kernel(const float* __restrict__ scores,
                                   const int* __restrict__ seg,
                                   float* __restrict__ out) {
    const int s = blockIdx.x;
    const int lane = threadIdx.x;
    int lo = 0, hi = NP;
    while (lo < hi) { int mid = (lo + hi) >> 1; if (seg[mid] < s) lo = mid + 1; else hi = mid; }
    const int start = lo;
    int lo2 = start, hi2 = NP;
    while (lo2 < hi2) { int mid = (lo2 + hi2) >> 1; if (seg[mid] <= s) lo2 = mid + 1; else hi2 = mid; }
    const int end = lo2;

    float m = 0.f;  // epsilon logit 0 participates in the max
    for (int i = start + lane; i < end; i += 64) m = fmaxf(m, scores[i]);
#pragma unroll
    for (int msk = 1; msk < 64; msk <<= 1) m = fmaxf(m, __shfl_xor(m, msk));

    float sum = 0.f;
    for (int i = start + lane; i < end; i += 64) sum += __expf(scores[i] - m);
#pragma unroll
    for (int msk = 1; msk < 64; msk <<= 1) sum += __shfl_xor(sum, msk);

    const float epse = __expf(-m);
    const float inv  = 1.f / (sum + epse);
    for (int i = start + lane; i < end; i += 64) out[i] = __expf(scores[i] - m) * inv;
    if (lane == 0) out[NP + s] = epse * inv;
}

// ---------------------------------------------------------------------------
extern "C" void kernel_launch(void* const* d_in, const int* in_sizes, int n_in,
                              void* d_out, int out_size, void* d_ws, size_t ws_size,
                              hipStream_t stream) {
    const float* gi     = (const float*)d_in[0];
    const float* mscore = (const float*)d_in[1];
    const float* spk    = (const float*)d_in[2];
    const float* W1     = (const float*)d_in[3];
    const float* b1     = (const float*)d_in[4];
    const float* W2     = (const float*)d_in[5];
    const float* b2     = (const float*)d_in[6];
    const int*   mids   = (const int*)d_in[7];
    const int*   aids   = (const int*)d_in[8];
    const int*   slab   = (const int*)d_in[9];
    const int*   segs   = (const int*)d_in[10];
    float* out = (float*)d_out;

    char* w = (char*)d_ws;
    u16*   gbf    = (u16*)w;                               // 18,874,368 B
    u16*   wpack  = (u16*)(w + 18874368);                  //  2,211,840 B (3 segs)
    float* APre   = (float*)(w + 21086208);                //  5,242,880 B
    float* scores = (float*)(w + 26329088);                //    131,072 B
    float* phib   = (float*)(w + 26460160);                //      1,920 B
    float* w2pad  = (float*)(w + 26462080);                //        640 B

    prep_kernel<<<dim3(543), dim3(256), 0, stream>>>(W1, spk, b1, W2, wpack, phib, w2pad);
    gemm_pre_kernel<<<dim3(256, 2), dim3(256), 0, stream>>>(gi, wpack + SEG_ELEMS, gbf, APre);
    gemm_pairs_kernel<<<dim3(512), dim3(128), 0, stream>>>(gbf, wpack, APre, phib, w2pad,
                                                           mscore, b2, mids, aids, slab, scores);
    seg_softmax_kernel<<<dim3(NSEG), dim3(64), 0, stream>>>(scores, segs, out);
}